// Round 6
// baseline (307.629 us; speedup 1.0000x reference)
//
#include <hip/hip_runtime.h>
#include <hip/hip_bf16.h>
#include <hip/hip_fp16.h>

// ---- types ----
typedef _Float16 f16x8 __attribute__((ext_vector_type(8)));
typedef float f32x4 __attribute__((ext_vector_type(4)));
typedef unsigned short us8 __attribute__((ext_vector_type(8)));

#define AS1 __attribute__((address_space(1)))
#define AS3 __attribute__((address_space(3)))
#define MFMA16(a, b, c) __builtin_amdgcn_mfma_f32_16x16x32_f16(a, b, c, 0, 0, 0)
#define BARRIER asm volatile("s_barrier" ::: "memory")

// ---------------- fp32 -> fp16 convert (8 elems/thread) ----------------
__global__ __launch_bounds__(256) void cvt_f32_f16(const float* __restrict__ in,
                                                   unsigned short* __restrict__ out,
                                                   int n8) {
  int i = blockIdx.x * 256 + threadIdx.x;
  if (i >= n8) return;
  const float4* p = (const float4*)in + 2 * (size_t)i;
  float4 a = p[0], b = p[1];
  f16x8 h;
  h[0] = (_Float16)a.x; h[1] = (_Float16)a.y; h[2] = (_Float16)a.z; h[3] = (_Float16)a.w;
  h[4] = (_Float16)b.x; h[5] = (_Float16)b.y; h[6] = (_Float16)b.z; h[7] = (_Float16)b.w;
  *(f16x8*)(out + (size_t)i * 8) = h;
}

// ---------------- 128x128 2-phase NT GEMM (projections only) ----------------
template <int OMODE, bool RBIAS>
__global__ __launch_bounds__(256) void gemm_nt(const unsigned short* __restrict__ A, int lda,
                                               const unsigned short* __restrict__ B, int ldb,
                                               void* __restrict__ Cout, int ldc,
                                               const float* __restrict__ bias,
                                               int N, int K) {
  __shared__ __attribute__((aligned(16))) unsigned short As[128 * 64];
  __shared__ __attribute__((aligned(16))) unsigned short Bs[128 * 64];
  const int nbn = N >> 7;
  const int bm = blockIdx.x / nbn, bn = blockIdx.x % nbn;
  const int tid = threadIdx.x;
  const int w = tid >> 6, l = tid & 63;
  const int wr = w >> 1, wc = w & 1;
  const int lr = l & 15, lg = l >> 4;

  const unsigned short* Ab = A + (size_t)bm * 128 * lda;
  const unsigned short* Bb = B + (size_t)bn * 128 * ldb;

  f32x4 acc[4][4] = {};

  auto ldfrag = [&](const unsigned short* base, int row, int kk) {
    int off = row * 128 + kk * 64 + lg * 16;
    off ^= (row & 7) << 4;
    return *(const f16x8*)((const unsigned char*)base + off);
  };

  for (int kt = 0; kt < K; kt += 64) {
#pragma unroll
    for (int i = 0; i < 4; ++i) {
      const int c = i * 256 + w * 64 + l;
      const int row = c >> 3, col = (((c & 7) ^ (row & 7)) << 3);
      __builtin_amdgcn_global_load_lds((const AS1 void*)(Ab + (size_t)row * lda + kt + col),
                                       (AS3 void*)(As + (i * 256 + w * 64) * 8), 16, 0, 0);
    }
#pragma unroll
    for (int i = 0; i < 4; ++i) {
      const int c = i * 256 + w * 64 + l;
      const int row = c >> 3, col = (((c & 7) ^ (row & 7)) << 3);
      __builtin_amdgcn_global_load_lds((const AS1 void*)(Bb + (size_t)row * ldb + kt + col),
                                       (AS3 void*)(Bs + (i * 256 + w * 64) * 8), 16, 0, 0);
    }
    __syncthreads();
#pragma unroll
    for (int kk = 0; kk < 2; ++kk) {
      f16x8 af[4], bf[4];
#pragma unroll
      for (int mi = 0; mi < 4; ++mi) af[mi] = ldfrag(As, wr * 64 + mi * 16 + lr, kk);
#pragma unroll
      for (int ni = 0; ni < 4; ++ni) bf[ni] = ldfrag(Bs, wc * 64 + ni * 16 + lr, kk);
#pragma unroll
      for (int mi = 0; mi < 4; ++mi)
#pragma unroll
        for (int ni = 0; ni < 4; ++ni)
          acc[mi][ni] = __builtin_amdgcn_mfma_f32_16x16x32_f16(af[mi], bf[ni], acc[mi][ni], 0, 0, 0);
    }
    __syncthreads();
  }

#pragma unroll
  for (int mi = 0; mi < 4; ++mi) {
#pragma unroll
    for (int r = 0; r < 4; ++r) {
      const int row = bm * 128 + wr * 64 + mi * 16 + lg * 4 + r;
      const float badd = RBIAS ? bias[row] : 0.0f;
#pragma unroll
      for (int ni = 0; ni < 4; ++ni) {
        const int col = bn * 128 + wc * 64 + ni * 16 + lr;
        float v = acc[mi][ni][r] + badd;
        if constexpr (OMODE == 0)
          ((unsigned short*)Cout)[(size_t)row * ldc + col] =
              __builtin_bit_cast(unsigned short, (_Float16)v);
        else
          ((float*)Cout)[(size_t)row * ldc + col] = v;
      }
    }
  }
}

// ============ co-resident NT GEMM, BK=32, 2-buffer, vmcnt(0)/tile ============
// C[M,N] = A[M,K]*B[N,K]^T. Tile 256x128: 4 waves (2m x 2n), per-wave 128x64.
// 256 thr, LDS 48KB, ~240 total regs -> 2 blocks/CU; each SIMD hosts 2 waves
// from INDEPENDENT blocks, so one block's vmcnt(0)+barrier drain is hidden by
// the sibling block's MFMAs (m114 overlap) instead of deep pipelining.
// Tile t+1 is staged (global_load_lds, pre-swizzled source) at tile t's start
// into the other buffer (consumed one barrier earlier); end-of-tile does
// vmcnt(0)+barrier. LDS rows 64B; slot bits[5:4] XOR (row>>1)&3 both sides.
// EPI: 0 = fp16 store; 2 = fp16 store of (mask ? exp(s) : 0)  (softmax
// normalization + V-bias are absorbed by the downstream LayerNorm).
template <int EPI, int KSP>
__global__ __launch_bounds__(256, 2) void gemmk(
    const unsigned short* __restrict__ A, int lda, size_t sAz,
    const unsigned short* __restrict__ B, int ldb, size_t sBz,
    unsigned short* __restrict__ Cout, int ldc, size_t sCz, size_t sCk,
    const int* __restrict__ mask, int mS,
    int NT, int KOFF, int XC, int WBM, int WBN) {
  constexpr int RA = 4;                 // A stage rounds (256 rows / 64)
  constexpr int RB = 2;                 // B stage rounds (128 rows / 64)
  constexpr int BUFSZ = 16384 + 8192;   // A region + B region
  __shared__ __attribute__((aligned(16))) unsigned char lds[2 * BUFSZ];

  const int tid = threadIdx.x;
  const int wv = tid >> 6, l = tid & 63;
  const int wm = wv >> 1, wn = wv & 1;
  const int lr = l & 15, lg = l >> 4;

  const int yi = blockIdx.y;
  const int z = yi / KSP, ks = yi % KSP;

  const int bid = blockIdx.x;
  const int xcd = bid & 7, ii = bid >> 3;
  const int bm = (xcd / XC) * WBM + ii / WBN;
  const int bn = (xcd % XC) * WBN + ii % WBN;

  const unsigned short* Ab = A + z * sAz + (size_t)ks * KOFF + (size_t)bm * 256 * lda;
  const unsigned short* Bb = B + z * sBz + (size_t)ks * KOFF + (size_t)(bn * 128) * ldb;

  // thread-constant LDS read bases (swizzle folded; mf/nf steps are +1024 B)
  const int xr = ((lr >> 1) & 3) << 4;
  const int aoff = ((wm * 128 + lr) << 6) + ((lg << 4) ^ xr);
  const int boff = 16384 + ((wn * 64 + lr) << 6) + ((lg << 4) ^ xr);

  // staging: round r covers rows r*64 + (tid>>2); col slot pre-swizzled with
  // (row>>1)&3 = (tid>>3)&3  (round offsets are multiples of 4 rows).
  const int scol = ((tid & 3) ^ ((tid >> 3) & 3)) << 3;
  const int srow = tid >> 2;
  const unsigned short* sa[RA];
  const unsigned short* sb[RB];
#pragma unroll
  for (int r = 0; r < RA; ++r) sa[r] = Ab + (size_t)(srow + r * 64) * lda + scol;
#pragma unroll
  for (int r = 0; r < RB; ++r) sb[r] = Bb + (size_t)(srow + r * 64) * ldb + scol;
  const int dA = wv * 1024;  // wave-uniform LDS dest within a stage round

  auto stageAll = [&](int eoff, int bo) {
#pragma unroll
    for (int r = 0; r < RA; ++r)
      __builtin_amdgcn_global_load_lds((const AS1 void*)(sa[r] + eoff),
                                       (AS3 void*)(lds + bo + r * 4096 + dA), 16, 0, 0);
#pragma unroll
    for (int r = 0; r < RB; ++r)
      __builtin_amdgcn_global_load_lds((const AS1 void*)(sb[r] + eoff),
                                       (AS3 void*)(lds + bo + 16384 + r * 4096 + dA), 16, 0, 0);
  };

  f32x4 acc[8][4] = {};

  // prologue: tile0 -> buf0, tile1 -> buf1; wait tile0 (keep tile1 in flight)
  stageAll(0, 0);
  stageAll(32, BUFSZ);
  asm volatile("s_waitcnt vmcnt(6)" ::: "memory");
  BARRIER;

  int bo = 0;
  for (int t = 0; t < NT; ++t, bo ^= BUFSZ) {
    const unsigned char* pa = lds + bo + aoff;
    const unsigned char* pb = lds + bo + boff;
    f16x8 a0 = *(const f16x8*)(pa);
    f16x8 a1 = *(const f16x8*)(pa + 1024);
    f16x8 a2 = *(const f16x8*)(pa + 2048);
    f16x8 a3 = *(const f16x8*)(pa + 3072);
    f16x8 b0 = *(const f16x8*)(pb);
    f16x8 b1 = *(const f16x8*)(pb + 1024);
    f16x8 b2 = *(const f16x8*)(pb + 2048);
    f16x8 b3 = *(const f16x8*)(pb + 3072);
    // stage tile t+1 into the other buffer (its old tile was consumed at the
    // end of tile t-1). Skipped at t=0: the other buffer still holds tile1.
    if (t >= 1 && t + 1 < NT) stageAll((t + 1) * 32, bo ^ BUFSZ);
    BARRIER;
    __builtin_amdgcn_s_setprio(1);
    acc[0][0] = MFMA16(a0, b0, acc[0][0]);
    acc[0][1] = MFMA16(a0, b1, acc[0][1]);
    acc[0][2] = MFMA16(a0, b2, acc[0][2]);
    acc[0][3] = MFMA16(a0, b3, acc[0][3]);
    acc[1][0] = MFMA16(a1, b0, acc[1][0]);
    acc[1][1] = MFMA16(a1, b1, acc[1][1]);
    acc[1][2] = MFMA16(a1, b2, acc[1][2]);
    acc[1][3] = MFMA16(a1, b3, acc[1][3]);
    acc[2][0] = MFMA16(a2, b0, acc[2][0]);
    acc[2][1] = MFMA16(a2, b1, acc[2][1]);
    acc[2][2] = MFMA16(a2, b2, acc[2][2]);
    acc[2][3] = MFMA16(a2, b3, acc[2][3]);
    acc[3][0] = MFMA16(a3, b0, acc[3][0]);
    acc[3][1] = MFMA16(a3, b1, acc[3][1]);
    acc[3][2] = MFMA16(a3, b2, acc[3][2]);
    acc[3][3] = MFMA16(a3, b3, acc[3][3]);
    f16x8 a4 = *(const f16x8*)(pa + 4096);
    f16x8 a5 = *(const f16x8*)(pa + 5120);
    f16x8 a6 = *(const f16x8*)(pa + 6144);
    f16x8 a7 = *(const f16x8*)(pa + 7168);
    acc[4][0] = MFMA16(a4, b0, acc[4][0]);
    acc[4][1] = MFMA16(a4, b1, acc[4][1]);
    acc[4][2] = MFMA16(a4, b2, acc[4][2]);
    acc[4][3] = MFMA16(a4, b3, acc[4][3]);
    acc[5][0] = MFMA16(a5, b0, acc[5][0]);
    acc[5][1] = MFMA16(a5, b1, acc[5][1]);
    acc[5][2] = MFMA16(a5, b2, acc[5][2]);
    acc[5][3] = MFMA16(a5, b3, acc[5][3]);
    acc[6][0] = MFMA16(a6, b0, acc[6][0]);
    acc[6][1] = MFMA16(a6, b1, acc[6][1]);
    acc[6][2] = MFMA16(a6, b2, acc[6][2]);
    acc[6][3] = MFMA16(a6, b3, acc[6][3]);
    acc[7][0] = MFMA16(a7, b0, acc[7][0]);
    acc[7][1] = MFMA16(a7, b1, acc[7][1]);
    acc[7][2] = MFMA16(a7, b2, acc[7][2]);
    acc[7][3] = MFMA16(a7, b3, acc[7][3]);
    __builtin_amdgcn_s_setprio(0);
    if (t + 1 < NT) {
      asm volatile("s_waitcnt vmcnt(0)" ::: "memory");
      BARRIER;
    }
  }

  // epilogue: C/D frag col=lr, row=4*lg+reg
  const size_t crow0 = (size_t)bm * 256 + wm * 128;
  const int ccol0 = bn * 128 + wn * 64;
  unsigned short* Cz = Cout + z * sCz + ks * sCk;
  int mk[4] = {1, 1, 1, 1};
  if constexpr (EPI == 2) {
#pragma unroll
    for (int nf = 0; nf < 4; ++nf)
      mk[nf] = mask[(size_t)z * mS + ccol0 + nf * 16 + lr];
  }
#pragma unroll
  for (int mf = 0; mf < 8; ++mf) {
#pragma unroll
    for (int rr = 0; rr < 4; ++rr) {
      const size_t rb = (crow0 + mf * 16 + lg * 4 + rr) * (size_t)ldc;
#pragma unroll
      for (int nf = 0; nf < 4; ++nf) {
        const int col = ccol0 + nf * 16 + lr;
        float v = acc[mf][nf][rr];
        if constexpr (EPI == 2) v = mk[nf] ? __expf(v) : 0.0f;
        Cz[rb + col] = __builtin_bit_cast(unsigned short, (_Float16)v);
      }
    }
  }
}

// -------- LayerNorm + output head; sums 2 fp16 split-K partials ----------
__device__ inline float block_sum(float v, float* sh, int t) {
#pragma unroll
  for (int o = 32; o; o >>= 1) v += __shfl_xor(v, o);
  __syncthreads();
  if ((t & 63) == 0) sh[t >> 6] = v;
  __syncthreads();
  return sh[0] + sh[1] + sh[2] + sh[3];
}

__global__ __launch_bounds__(256) void ln_head(const unsigned short* __restrict__ yp,
                                               size_t zoff, size_t koff,
                                               const float* __restrict__ gam,
                                               const float* __restrict__ bet,
                                               const float* __restrict__ wo,
                                               const float* __restrict__ bo,
                                               float* __restrict__ out) {
  const int z = blockIdx.y;
  const size_t rbase = (size_t)z * zoff + (size_t)blockIdx.x * 768;
  const _Float16* y0 = (const _Float16*)yp + rbase;
  const _Float16* y1 = y0 + koff;
  const int t = threadIdx.x;
  float a0 = (float)y0[t] + (float)y1[t];
  float a1 = (float)y0[t + 256] + (float)y1[t + 256];
  float a2 = (float)y0[t + 512] + (float)y1[t + 512];
  __shared__ float sh[4];
  float s = block_sum(a0 + a1 + a2, sh, t);
  float mu = s * (1.0f / 768.0f);
  float d0 = a0 - mu, d1 = a1 - mu, d2 = a2 - mu;
  float q = block_sum(d0 * d0 + d1 * d1 + d2 * d2, sh, t);
  float rs = rsqrtf(q * (1.0f / 768.0f) + 1e-5f);
  float o = (d0 * rs * gam[t] + bet[t]) * wo[t] +
            (d1 * rs * gam[t + 256] + bet[t + 256]) * wo[t + 256] +
            (d2 * rs * gam[t + 512] + bet[t + 512]) * wo[t + 512];
  o = block_sum(o, sh, t);
  if (t == 0) out[(size_t)z * 8192 + blockIdx.x] = o + bo[0];
}

// ---------------- launch ----------------
extern "C" void kernel_launch(void* const* d_in, const int* in_sizes, int n_in,
                              void* d_out, int out_size, void* d_ws, size_t ws_size,
                              hipStream_t stream) {
  const float* x  = (const float*)d_in[0];
  const int*   am = (const int*)d_in[1];
  const float* Wk = (const float*)d_in[2];
  const float* Wv = (const float*)d_in[3];
  const float* bv = (const float*)d_in[4];
  const float* Q  = (const float*)d_in[5];
  const float* gam = (const float*)d_in[6];
  const float* bet = (const float*)d_in[7];
  const float* wo  = (const float*)d_in[8];
  const float* bo  = (const float*)d_in[9];
  float* out = (float*)d_out;

  const int S = 4096, D = 768, C = 8192;
  const size_t nX = (size_t)2 * S * D;
  const size_t nW = (size_t)D * D;
  const size_t nQ = (size_t)C * D;
  const size_t nP = (size_t)C * S;
  const size_t nY = (size_t)C * D;

  unsigned short* xb  = (unsigned short*)d_ws;
  unsigned short* Wkb = xb + nX;
  unsigned short* Wvb = Wkb + nW;
  unsigned short* Qb  = Wvb + nW;
  unsigned short* Kb  = Qb + nQ;
  unsigned short* Vt  = Kb + nX;  // [D][2*S]
  unsigned short* P   = Vt + nX;

  const size_t bigNeed = ((nX * 4 + nW * 2 + 2 * nP) * 2 + 2 * nY * 4);
  const bool big = ws_size >= bigNeed;

  cvt_f32_f16<<<(int)(nX / 8 / 256), 256, 0, stream>>>(x, xb, (int)(nX / 8));
  cvt_f32_f16<<<(int)(nW / 8 / 256), 256, 0, stream>>>(Wk, Wkb, (int)(nW / 8));
  cvt_f32_f16<<<(int)(nW / 8 / 256), 256, 0, stream>>>(Wv, Wvb, (int)(nW / 8));
  cvt_f32_f16<<<(int)(nQ / 8 / 256), 256, 0, stream>>>(Q, Qb, (int)(nQ / 8));

  gemm_nt<0, false><<<(8192 / 128) * (768 / 128), 256, 0, stream>>>(
      xb, D, Wkb, D, Kb, D, nullptr, 768, D);
  gemm_nt<0, true><<<(768 / 128) * (8192 / 128), 256, 0, stream>>>(
      Wvb, D, xb, D, Vt, 2 * S, bv, 2 * S, D);

  if (big) {
    unsigned short* yp = P + 2 * nP;  // [ks(2)][z(2)][C][D] fp16 partials
    // scores+mask+exp fused, both batches. 2048 blocks, 2 blocks/CU.
    // M: 32 bm, N: 32 bn (tile 256x128); per XCD 8bm x 16bn.
    gemmk<2, 1><<<dim3(1024, 2), 256, 0, stream>>>(
        Qb, D, 0, Kb, D, (size_t)S * D, P, S, nP, 0, am, S, 24, 0, 2, 8, 16);
    // PV split-K=2: per (z,ks) 32 bm x 6 bn = 192 blocks; 768 total.
    gemmk<0, 2><<<dim3(192, 4), 256, 0, stream>>>(
        P, S, nP, Vt, 2 * S, (size_t)S, yp, D, nY, 2 * nY, nullptr, 0, 64, 2048, 2, 8, 3);
    ln_head<<<dim3(C, 2), 256, 0, stream>>>(yp, nY, 2 * nY, gam, bet, wo, bo, out);
  } else {
    unsigned short* yp = P + nP;  // [ks(2)][C][D] fp16 partials
    for (int b = 0; b < 2; ++b) {
      gemmk<2, 1><<<dim3(1024, 1), 256, 0, stream>>>(
          Qb, D, 0, Kb + (size_t)b * S * D, D, 0, P, S, 0, 0,
          am + (size_t)b * S, S, 24, 0, 2, 8, 16);
      gemmk<0, 2><<<dim3(192, 2), 256, 0, stream>>>(
          P, S, 0, Vt + (size_t)b * S, 2 * S, 0, yp, D, 0, nY, nullptr, 0, 64, 2048, 2, 8, 3);
      ln_head<<<dim3(C, 1), 256, 0, stream>>>(yp, 0, nY, gam, bet, wo, bo, out + (size_t)b * C);
    }
  }
}

// Round 8
// 239.124 us; speedup vs baseline: 1.2865x; 1.2865x over previous
//
#include <hip/hip_runtime.h>
#include <hip/hip_bf16.h>
#include <hip/hip_fp16.h>

// ---- types ----
typedef _Float16 f16x8 __attribute__((ext_vector_type(8)));
typedef _Float16 f16x4 __attribute__((ext_vector_type(4)));
typedef float f32x4 __attribute__((ext_vector_type(4)));

#define AS1 __attribute__((address_space(1)))
#define AS3 __attribute__((address_space(3)))
#define MFMA16(a, b, c) __builtin_amdgcn_mfma_f32_16x16x32_f16(a, b, c, 0, 0, 0)
#define BARRIER asm volatile("s_barrier" ::: "memory")

// -------- mask prefix-scan: per b, compact valid indices + meta --------
// meta[2b]=valid count, meta[2b+1]=ns_pad (valid rounded up to 256, min 256)
__global__ __launch_bounds__(256) void maskscan(const int* __restrict__ am,
                                                int* __restrict__ idx,
                                                int* __restrict__ meta) {
  const int b = blockIdx.x, t = threadIdx.x;
  const int* m = am + (size_t)b * 4096;
  int* ix = idx + (size_t)b * 4096;
  __shared__ int cnt[256];
  __shared__ int pre[257];
  int loc[16], c = 0;
#pragma unroll
  for (int j = 0; j < 16; ++j) {
    loc[j] = m[t * 16 + j];
    c += (loc[j] != 0);
  }
  cnt[t] = c;
  __syncthreads();
  if (t == 0) {
    pre[0] = 0;
    for (int i = 0; i < 256; ++i) pre[i + 1] = pre[i] + cnt[i];
  }
  __syncthreads();
  int p = pre[t];
#pragma unroll
  for (int j = 0; j < 16; ++j)
    if (loc[j]) ix[p++] = t * 16 + j;
  const int valid = pre[256];
  int nsp = ((valid + 255) >> 8) << 8;
  if (nsp < 256) nsp = 256;
  for (int j = valid + t; j < nsp; j += 256) ix[j] = -1;  // pad slots
  if (t == 0) { meta[2 * b] = valid; meta[2 * b + 1] = nsp; }
}

// -------- gather valid x rows + fp32->fp16 convert: xc[b][slot][:] --------
__global__ __launch_bounds__(192) void gather_cvt(const float* __restrict__ x,
                                                  const int* __restrict__ idx,
                                                  const int* __restrict__ meta,
                                                  unsigned short* __restrict__ xc) {
  const int b = blockIdx.y, row = blockIdx.x, t = threadIdx.x;
  if (row >= meta[2 * b + 1]) return;
  const int src = idx[(size_t)b * 4096 + row];
  unsigned short* dst = xc + ((size_t)b * 4096 + row) * 768 + t * 4;
  f16x4 h;
  if (src < 0) {
    h[0] = h[1] = h[2] = h[3] = (_Float16)0.0f;
  } else {
    float4 v = *(const float4*)(x + ((size_t)b * 4096 + src) * 768 + t * 4);
    h[0] = (_Float16)v.x; h[1] = (_Float16)v.y; h[2] = (_Float16)v.z; h[3] = (_Float16)v.w;
  }
  *(f16x4*)dst = h;
}

// ---------------- fp32 -> fp16 convert (8 elems/thread) ----------------
__global__ __launch_bounds__(256) void cvt_f32_f16(const float* __restrict__ in,
                                                   unsigned short* __restrict__ out,
                                                   int n8) {
  int i = blockIdx.x * 256 + threadIdx.x;
  if (i >= n8) return;
  const float4* p = (const float4*)in + 2 * (size_t)i;
  float4 a = p[0], b = p[1];
  f16x8 h;
  h[0] = (_Float16)a.x; h[1] = (_Float16)a.y; h[2] = (_Float16)a.z; h[3] = (_Float16)a.w;
  h[4] = (_Float16)b.x; h[5] = (_Float16)b.y; h[6] = (_Float16)b.z; h[7] = (_Float16)b.w;
  *(f16x8*)(out + (size_t)i * 8) = h;
}

// ---------------- 128x128 2-phase NT GEMM (projections) ----------------
// EXITD: 0 none; 1 skip M-tiles beyond ns_pad; 2 skip N-tiles beyond ns_pad.
template <int OMODE, bool RBIAS, int EXITD>
__global__ __launch_bounds__(256) void gemm_nt(const unsigned short* __restrict__ A, int lda,
                                               const unsigned short* __restrict__ B, int ldb,
                                               void* __restrict__ Cout, int ldc,
                                               const float* __restrict__ bias,
                                               const int* __restrict__ meta,
                                               int N, int K) {
  const int nbn = N >> 7;
  const int bm = blockIdx.x / nbn, bn = blockIdx.x % nbn;
  if constexpr (EXITD == 1) {
    if (((bm & 31) << 7) >= meta[2 * (bm >> 5) + 1]) return;
  } else if constexpr (EXITD == 2) {
    if (((bn & 31) << 7) >= meta[2 * (bn >> 5) + 1]) return;
  }
  __shared__ __attribute__((aligned(16))) unsigned short As[128 * 64];
  __shared__ __attribute__((aligned(16))) unsigned short Bs[128 * 64];
  const int tid = threadIdx.x;
  const int w = tid >> 6, l = tid & 63;
  const int wr = w >> 1, wc = w & 1;
  const int lr = l & 15, lg = l >> 4;

  const unsigned short* Ab = A + (size_t)bm * 128 * lda;
  const unsigned short* Bb = B + (size_t)bn * 128 * ldb;

  f32x4 acc[4][4] = {};

  auto ldfrag = [&](const unsigned short* base, int row, int kk) {
    int off = row * 128 + kk * 64 + lg * 16;
    off ^= (row & 7) << 4;
    return *(const f16x8*)((const unsigned char*)base + off);
  };

  for (int kt = 0; kt < K; kt += 64) {
#pragma unroll
    for (int i = 0; i < 4; ++i) {
      const int c = i * 256 + w * 64 + l;
      const int row = c >> 3, col = (((c & 7) ^ (row & 7)) << 3);
      __builtin_amdgcn_global_load_lds((const AS1 void*)(Ab + (size_t)row * lda + kt + col),
                                       (AS3 void*)(As + (i * 256 + w * 64) * 8), 16, 0, 0);
    }
#pragma unroll
    for (int i = 0; i < 4; ++i) {
      const int c = i * 256 + w * 64 + l;
      const int row = c >> 3, col = (((c & 7) ^ (row & 7)) << 3);
      __builtin_amdgcn_global_load_lds((const AS1 void*)(Bb + (size_t)row * ldb + kt + col),
                                       (AS3 void*)(Bs + (i * 256 + w * 64) * 8), 16, 0, 0);
    }
    __syncthreads();
#pragma unroll
    for (int kk = 0; kk < 2; ++kk) {
      f16x8 af[4], bf[4];
#pragma unroll
      for (int mi = 0; mi < 4; ++mi) af[mi] = ldfrag(As, wr * 64 + mi * 16 + lr, kk);
#pragma unroll
      for (int ni = 0; ni < 4; ++ni) bf[ni] = ldfrag(Bs, wc * 64 + ni * 16 + lr, kk);
#pragma unroll
      for (int mi = 0; mi < 4; ++mi)
#pragma unroll
        for (int ni = 0; ni < 4; ++ni)
          acc[mi][ni] = __builtin_amdgcn_mfma_f32_16x16x32_f16(af[mi], bf[ni], acc[mi][ni], 0, 0, 0);
    }
    __syncthreads();
  }

#pragma unroll
  for (int mi = 0; mi < 4; ++mi) {
#pragma unroll
    for (int r = 0; r < 4; ++r) {
      const int row = bm * 128 + wr * 64 + mi * 16 + lg * 4 + r;
      const float badd = RBIAS ? bias[row] : 0.0f;
#pragma unroll
      for (int ni = 0; ni < 4; ++ni) {
        const int col = bn * 128 + wc * 64 + ni * 16 + lr;
        float v = acc[mi][ni][r] + badd;
        if constexpr (OMODE == 0)
          ((unsigned short*)Cout)[(size_t)row * ldc + col] =
              __builtin_bit_cast(unsigned short, (_Float16)v);
        else
          ((float*)Cout)[(size_t)row * ldc + col] = v;
      }
    }
  }
}

// ============ co-resident NT GEMM, BK=32, 2-buffer, vmcnt(0)/tile ============
// Tile 256x128: 4 waves (2m x 2n), per-wave 128x64; 48KB LDS, 2 blocks/CU.
// EPI=2 (scores): NT fixed; exit when bn*128 >= ns_pad; store (col<valid ?
//   exp(s) : 0) as fp16 — softmax denom + V-bias absorbed by LayerNorm.
// EPI=0 (PV): K compacted at runtime: NT = ns_pad/64 (per split ns_pad/2),
//   k-offset ks*ns_pad/2.  bn interleaved across XCDs.
template <int EPI, int KSP>
__global__ __launch_bounds__(256, 2) void gemmk(
    const unsigned short* __restrict__ A, int lda, size_t sAz,
    const unsigned short* __restrict__ B, int ldb, size_t sBz,
    unsigned short* __restrict__ Cout, int ldc, size_t sCz, size_t sCk,
    const int* __restrict__ meta, int NTfix,
    int XC, int WBM, int WBN) {
  constexpr int RA = 4;
  constexpr int RB = 2;
  constexpr int BUFSZ = 16384 + 8192;
  __shared__ __attribute__((aligned(16))) unsigned char lds[2 * BUFSZ];

  const int tid = threadIdx.x;
  const int wv = tid >> 6, l = tid & 63;
  const int wm = wv >> 1, wn = wv & 1;
  const int lr = l & 15, lg = l >> 4;

  const int yi = blockIdx.y;
  const int z = yi / KSP, ks = yi % KSP;
  const int valid = meta[2 * z], nsp = meta[2 * z + 1];

  const int bid = blockIdx.x;
  const int xcd = bid & 7, ii = bid >> 3;
  const int bm = (xcd / XC) * WBM + ii / WBN;
  const int bn = (ii % WBN) * XC + (xcd % XC);

  int NT, koff;
  if constexpr (EPI == 2) {
    NT = NTfix; koff = 0;
    if ((bn << 7) >= nsp) return;
  } else {
    NT = nsp >> 6;
    koff = ks * (nsp >> 1);
  }

  const unsigned short* Ab = A + z * sAz + koff + (size_t)bm * 256 * lda;
  const unsigned short* Bb = B + z * sBz + koff + (size_t)(bn * 128) * ldb;

  const int xr = ((lr >> 1) & 3) << 4;
  const int aoff = ((wm * 128 + lr) << 6) + ((lg << 4) ^ xr);
  const int boff = 16384 + ((wn * 64 + lr) << 6) + ((lg << 4) ^ xr);

  const int scol = ((tid & 3) ^ ((tid >> 3) & 3)) << 3;
  const int srow = tid >> 2;
  const unsigned short* sa[RA];
  const unsigned short* sb[RB];
#pragma unroll
  for (int r = 0; r < RA; ++r) sa[r] = Ab + (size_t)(srow + r * 64) * lda + scol;
#pragma unroll
  for (int r = 0; r < RB; ++r) sb[r] = Bb + (size_t)(srow + r * 64) * ldb + scol;
  const int dA = wv * 1024;

  auto stageAll = [&](int eoff, int bo) {
#pragma unroll
    for (int r = 0; r < RA; ++r)
      __builtin_amdgcn_global_load_lds((const AS1 void*)(sa[r] + eoff),
                                       (AS3 void*)(lds + bo + r * 4096 + dA), 16, 0, 0);
#pragma unroll
    for (int r = 0; r < RB; ++r)
      __builtin_amdgcn_global_load_lds((const AS1 void*)(sb[r] + eoff),
                                       (AS3 void*)(lds + bo + 16384 + r * 4096 + dA), 16, 0, 0);
  };

  f32x4 acc[8][4] = {};

  stageAll(0, 0);
  stageAll(32, BUFSZ);
  asm volatile("s_waitcnt vmcnt(6)" ::: "memory");
  BARRIER;

  int bo = 0;
  for (int t = 0; t < NT; ++t, bo ^= BUFSZ) {
    const unsigned char* pa = lds + bo + aoff;
    const unsigned char* pb = lds + bo + boff;
    f16x8 a0 = *(const f16x8*)(pa);
    f16x8 a1 = *(const f16x8*)(pa + 1024);
    f16x8 a2 = *(const f16x8*)(pa + 2048);
    f16x8 a3 = *(const f16x8*)(pa + 3072);
    f16x8 b0 = *(const f16x8*)(pb);
    f16x8 b1 = *(const f16x8*)(pb + 1024);
    f16x8 b2 = *(const f16x8*)(pb + 2048);
    f16x8 b3 = *(const f16x8*)(pb + 3072);
    if (t >= 1 && t + 1 < NT) stageAll((t + 1) * 32, bo ^ BUFSZ);
    BARRIER;
    __builtin_amdgcn_s_setprio(1);
    acc[0][0] = MFMA16(a0, b0, acc[0][0]);
    acc[0][1] = MFMA16(a0, b1, acc[0][1]);
    acc[0][2] = MFMA16(a0, b2, acc[0][2]);
    acc[0][3] = MFMA16(a0, b3, acc[0][3]);
    acc[1][0] = MFMA16(a1, b0, acc[1][0]);
    acc[1][1] = MFMA16(a1, b1, acc[1][1]);
    acc[1][2] = MFMA16(a1, b2, acc[1][2]);
    acc[1][3] = MFMA16(a1, b3, acc[1][3]);
    acc[2][0] = MFMA16(a2, b0, acc[2][0]);
    acc[2][1] = MFMA16(a2, b1, acc[2][1]);
    acc[2][2] = MFMA16(a2, b2, acc[2][2]);
    acc[2][3] = MFMA16(a2, b3, acc[2][3]);
    acc[3][0] = MFMA16(a3, b0, acc[3][0]);
    acc[3][1] = MFMA16(a3, b1, acc[3][1]);
    acc[3][2] = MFMA16(a3, b2, acc[3][2]);
    acc[3][3] = MFMA16(a3, b3, acc[3][3]);
    f16x8 a4 = *(const f16x8*)(pa + 4096);
    f16x8 a5 = *(const f16x8*)(pa + 5120);
    f16x8 a6 = *(const f16x8*)(pa + 6144);
    f16x8 a7 = *(const f16x8*)(pa + 7168);
    acc[4][0] = MFMA16(a4, b0, acc[4][0]);
    acc[4][1] = MFMA16(a4, b1, acc[4][1]);
    acc[4][2] = MFMA16(a4, b2, acc[4][2]);
    acc[4][3] = MFMA16(a4, b3, acc[4][3]);
    acc[5][0] = MFMA16(a5, b0, acc[5][0]);
    acc[5][1] = MFMA16(a5, b1, acc[5][1]);
    acc[5][2] = MFMA16(a5, b2, acc[5][2]);
    acc[5][3] = MFMA16(a5, b3, acc[5][3]);
    acc[6][0] = MFMA16(a6, b0, acc[6][0]);
    acc[6][1] = MFMA16(a6, b1, acc[6][1]);
    acc[6][2] = MFMA16(a6, b2, acc[6][2]);
    acc[6][3] = MFMA16(a6, b3, acc[6][3]);
    acc[7][0] = MFMA16(a7, b0, acc[7][0]);
    acc[7][1] = MFMA16(a7, b1, acc[7][1]);
    acc[7][2] = MFMA16(a7, b2, acc[7][2]);
    acc[7][3] = MFMA16(a7, b3, acc[7][3]);
    __builtin_amdgcn_s_setprio(0);
    if (t + 1 < NT) {
      asm volatile("s_waitcnt vmcnt(0)" ::: "memory");
      BARRIER;
    }
  }

  // epilogue: C/D frag col=lr, row=4*lg+reg
  const size_t crow0 = (size_t)bm * 256 + wm * 128;
  const int ccol0 = bn * 128 + wn * 64;
  unsigned short* Cz = Cout + z * sCz + ks * sCk;
  int mk[4] = {1, 1, 1, 1};
  if constexpr (EPI == 2) {
#pragma unroll
    for (int nf = 0; nf < 4; ++nf)
      mk[nf] = (ccol0 + nf * 16 + lr) < valid;
  }
#pragma unroll
  for (int mf = 0; mf < 8; ++mf) {
#pragma unroll
    for (int rr = 0; rr < 4; ++rr) {
      const size_t rb = (crow0 + mf * 16 + lg * 4 + rr) * (size_t)ldc;
#pragma unroll
      for (int nf = 0; nf < 4; ++nf) {
        const int col = ccol0 + nf * 16 + lr;
        float v = acc[mf][nf][rr];
        if constexpr (EPI == 2) v = mk[nf] ? __expf(v) : 0.0f;
        Cz[rb + col] = __builtin_bit_cast(unsigned short, (_Float16)v);
      }
    }
  }
}

// -------- LayerNorm + output head; sums 2 fp16 split-K partials ----------
__device__ inline float block_sum(float v, float* sh, int t) {
#pragma unroll
  for (int o = 32; o; o >>= 1) v += __shfl_xor(v, o);
  __syncthreads();
  if ((t & 63) == 0) sh[t >> 6] = v;
  __syncthreads();
  return sh[0] + sh[1] + sh[2] + sh[3];
}

__global__ __launch_bounds__(256) void ln_head(const unsigned short* __restrict__ yp,
                                               size_t koff,
                                               const float* __restrict__ gam,
                                               const float* __restrict__ bet,
                                               const float* __restrict__ wo,
                                               const float* __restrict__ bo,
                                               float* __restrict__ out) {
  const size_t rbase = (size_t)blockIdx.x * 768;
  const _Float16* y0 = (const _Float16*)yp + rbase;
  const _Float16* y1 = y0 + koff;
  const int t = threadIdx.x;
  float a0 = (float)y0[t] + (float)y1[t];
  float a1 = (float)y0[t + 256] + (float)y1[t + 256];
  float a2 = (float)y0[t + 512] + (float)y1[t + 512];
  __shared__ float sh[4];
  float s = block_sum(a0 + a1 + a2, sh, t);
  float mu = s * (1.0f / 768.0f);
  float d0 = a0 - mu, d1 = a1 - mu, d2 = a2 - mu;
  float q = block_sum(d0 * d0 + d1 * d1 + d2 * d2, sh, t);
  float rs = rsqrtf(q * (1.0f / 768.0f) + 1e-5f);
  float o = (d0 * rs * gam[t] + bet[t]) * wo[t] +
            (d1 * rs * gam[t + 256] + bet[t + 256]) * wo[t + 256] +
            (d2 * rs * gam[t + 512] + bet[t + 512]) * wo[t + 512];
  o = block_sum(o, sh, t);
  if (t == 0) out[blockIdx.x] = o + bo[0];
}

// ---------------- launch ----------------
extern "C" void kernel_launch(void* const* d_in, const int* in_sizes, int n_in,
                              void* d_out, int out_size, void* d_ws, size_t ws_size,
                              hipStream_t stream) {
  const float* x  = (const float*)d_in[0];
  const int*   am = (const int*)d_in[1];
  const float* Wk = (const float*)d_in[2];
  const float* Wv = (const float*)d_in[3];
  const float* bv = (const float*)d_in[4];
  const float* Q  = (const float*)d_in[5];
  const float* gam = (const float*)d_in[6];
  const float* bet = (const float*)d_in[7];
  const float* wo  = (const float*)d_in[8];
  const float* bo  = (const float*)d_in[9];
  float* out = (float*)d_out;

  const int S = 4096, D = 768, C = 8192;
  const size_t nX = (size_t)2 * S * D;   // 6291456
  const size_t nW = (size_t)D * D;
  const size_t nQ = (size_t)C * D;
  const size_t nP = (size_t)C * S;
  const size_t nY = (size_t)C * D;

  // compact layout, total ~145 MB (proven ws >= ~237 MB in rounds 2-6):
  // xc(nX) Wkb(nW) Wvb(nW) Qb(nQ) Kb(nX) Vt(nX) P(nP) yp(2nY) idx meta
  unsigned short* xc  = (unsigned short*)d_ws;
  unsigned short* Wkb = xc + nX;
  unsigned short* Wvb = Wkb + nW;
  unsigned short* Qb  = Wvb + nW;
  unsigned short* Kb  = Qb + nQ;
  unsigned short* Vt  = Kb + nX;  // [D][2*S], valid cols per-b = ns_pad
  unsigned short* P   = Vt + nX;  // [C][S], reused per b
  unsigned short* yp  = P + nP;   // [ks(2)][C][D] fp16 partials, reused per b
  int* idx  = (int*)(yp + 2 * nY);
  int* meta = idx + 2 * 4096;

  // 0) mask scan + compact-gather x (fp16)
  maskscan<<<2, 256, 0, stream>>>(am, idx, meta);
  gather_cvt<<<dim3(4096, 2), 192, 0, stream>>>(x, idx, meta, xc);

  // 1) weight/Q converts
  cvt_f32_f16<<<(int)(nW / 8 / 256), 256, 0, stream>>>(Wk, Wkb, (int)(nW / 8));
  cvt_f32_f16<<<(int)(nW / 8 / 256), 256, 0, stream>>>(Wv, Wvb, (int)(nW / 8));
  cvt_f32_f16<<<(int)(nQ / 8 / 256), 256, 0, stream>>>(Q, Qb, (int)(nQ / 8));

  // 2) projections on compacted tokens (tiles beyond ns_pad exit)
  gemm_nt<0, false, 1><<<(8192 / 128) * (768 / 128), 256, 0, stream>>>(
      xc, D, Wkb, D, Kb, D, nullptr, meta, 768, D);
  gemm_nt<0, true, 2><<<(768 / 128) * (8192 / 128), 256, 0, stream>>>(
      Wvb, D, xc, D, Vt, 2 * S, bv, meta, 2 * S, D);

  // 3) per batch: scores -> PV(split-K=2) -> LN+head  (P/yp reused)
  for (int b = 0; b < 2; ++b) {
    gemmk<2, 1><<<dim3(1024, 1), 256, 0, stream>>>(
        Qb, D, 0, Kb + (size_t)b * S * D, D, 0, P, S, 0, 0,
        meta + 2 * b, 24, 2, 8, 16);
    gemmk<0, 2><<<dim3(192, 2), 256, 0, stream>>>(
        P, S, 0, Vt + (size_t)b * S, 2 * S, 0, yp, D, 0, nY,
        meta + 2 * b, 0, 2, 8, 3);
    ln_head<<<dim3(C, 1), 256, 0, stream>>>(yp, nY, gam, bet, wo, bo, out + (size_t)b * C);
  }
}